// Round 6
// baseline (10952.717 us; speedup 1.0000x reference)
//
#include <hip/hip_runtime.h>
#include <hip/hip_bf16.h>

// SocialLSTM forward, MI355X gfx950 — persistent kernel, plain launch + manual
// grid barrier (grid 256 = 1 block/CU guaranteed co-resident; 46KB LDS, LB(256,1)).
// Dual-dtype float inputs (bf16 or f32) detected at runtime from W_soc.
// ws layout (bytes):
//   c_ws  f32[1024*64]      @ 0
//   Wt    bf16[256][4096]   @ 262144   (W_soc^T, [n][k])
//   Wgt   bf16[256][384]    @ 2359296  ([Wih;Whh]^T, [n][k])
//   bsocF f32[256]          @ 2555904
//   bgF   f32[256]          @ 2556928  (bih+bhh)
//   WoutF f32[128]          @ 2557952
//   WembF f32[128]          @ 2558464
//   bembF f32[64]           @ 2558976
//   boutF f32[2]            @ 2559232
//   bar   int               @ 2559240
//   flag  int               @ 2559244
//   Xc    f32[32][1024][2]  @ 2560000
//   zb    bf16[1024][384]   @ 2822144  (r cols 0-63, h cols 320-383)
//   hbB   bf16[1024][64]    @ 3608576  (compact h for pooling gathers)
//   Hbuf  bf16[1024][3136]  @ 3739648  (49 cells * 64 hid per row)
//   part  f32[8][1024*256]  @ 10162176 (K-split GEMM partials)

typedef short bf16x8 __attribute__((ext_vector_type(8)));
typedef float f32x4 __attribute__((ext_vector_type(4)));

#define WS_CW    0
#define WS_WT    262144
#define WS_WGT   2359296
#define WS_BSOC  2555904
#define WS_BG    2556928
#define WS_WOUT  2557952
#define WS_WEMB  2558464
#define WS_BEMB  2558976
#define WS_BOUT  2559232
#define WS_BAR   2559240
#define WS_FLAG  2559244
#define WS_XC    2560000
#define WS_ZB    2822144
#define WS_HBB   3608576
#define WS_HBUF  3739648
#define WS_PART  10162176

__device__ __forceinline__ float u2f(unsigned short u) {
    union { unsigned int i; float f; } v; v.i = ((unsigned int)u) << 16; return v.f;
}
__device__ __forceinline__ unsigned short f2b(float f) {
    __hip_bfloat16 hb = __float2bfloat16(f);
    return *(unsigned short*)&hb;
}
__device__ __forceinline__ float ldin(const void* p, int idx, int isf32) {
    return isf32 ? ((const float*)p)[idx] : u2f(((const unsigned short*)p)[idx]);
}
__device__ __forceinline__ int get_tpred(const int* p) {
    int v = p[0];
    if (v >= 0 && v <= 64) return v;
    float f = ((const float*)p)[0];
    if (f >= 0.f && f <= 64.f) return (int)f;
    float g = u2f(((const unsigned short*)p)[0]);
    if (g >= 0.f && g <= 64.f) return (int)g;
    return 31;
}

// ---------------- dtype detector ------------------------------------------
__global__ __launch_bounds__(256) void k_detect(const void* __restrict__ Wsoc,
                                                int* __restrict__ flag) {
    __shared__ int f;
    int tid = threadIdx.x;
    if (tid == 0) f = 0;
    __syncthreads();
    const unsigned short* p = (const unsigned short*)Wsoc;
    #pragma unroll
    for (int k = 0; k < 4; k++) {
        float v = u2f(p[tid * 4 + k]);
        if (!(v == v) || fabsf(v) > 1e20f) f = 1;
    }
    __syncthreads();
    if (tid == 0) flag[0] = f;
}

// ---------------- one-time prep (block-ranged, 237 blocks) ----------------
__global__ __launch_bounds__(256) void k_prep(char* __restrict__ ws,
                                              const void* __restrict__ X,
                                              const void* __restrict__ h0,
                                              const void* __restrict__ c0,
                                              const void* __restrict__ Wsoc,
                                              const void* __restrict__ Wih,
                                              const void* __restrict__ Whh,
                                              const void* __restrict__ bih,
                                              const void* __restrict__ bhh,
                                              const void* __restrict__ bsoc,
                                              const void* __restrict__ Wemb,
                                              const void* __restrict__ bemb,
                                              const void* __restrict__ Wout,
                                              const void* __restrict__ bout,
                                              void* __restrict__ out) {
    __shared__ __align__(16) unsigned short tile[32 * 264];
    int b = blockIdx.x, tid = threadIdx.x;
    int isf32 = *(const int*)(ws + WS_FLAG);
    if (b < 128) {                      // Wt = Wsoc^T
        unsigned short* Wt = (unsigned short*)(ws + WS_WT);
        int k0 = b * 32;
        if (isf32) {
            const float* W = (const float*)Wsoc;
            #pragma unroll
            for (int p = 0; p < 4; p++) {
                int kk = (tid >> 5) + p * 8, n8 = (tid & 31) * 8;
                #pragma unroll
                for (int q = 0; q < 8; q++)
                    tile[kk * 264 + n8 + q] = f2b(W[(k0 + kk) * 256 + n8 + q]);
            }
        } else {
            const unsigned short* W = (const unsigned short*)Wsoc;
            #pragma unroll
            for (int p = 0; p < 4; p++) {
                int kk = (tid >> 5) + p * 8, n8 = (tid & 31) * 8;
                *(uint4*)&tile[kk * 264 + n8] = *(const uint4*)(W + (k0 + kk) * 256 + n8);
            }
        }
        __syncthreads();
        unsigned int packed[16];
        #pragma unroll
        for (int q = 0; q < 16; q++) {
            unsigned int lo = tile[(2 * q) * 264 + tid];
            unsigned int hi = tile[(2 * q + 1) * 264 + tid];
            packed[q] = lo | (hi << 16);
        }
        uint4* dst = (uint4*)(Wt + (long)tid * 4096 + k0);
        #pragma unroll
        for (int p = 0; p < 4; p++)
            dst[p] = make_uint4(packed[4*p], packed[4*p+1], packed[4*p+2], packed[4*p+3]);
    } else if (b < 140) {               // Wgt = [Wih;Whh]^T
        unsigned short* Wgt = (unsigned short*)(ws + WS_WGT);
        int k0 = (b - 128) * 32;
        #pragma unroll
        for (int p = 0; p < 4; p++) {
            int kk = (tid >> 5) + p * 8, n8 = (tid & 31) * 8;
            int krow = k0 + kk;
            const void* src = (krow < 320) ? Wih : Whh;
            int srow = (krow < 320) ? krow : (krow - 320);
            #pragma unroll
            for (int q = 0; q < 8; q++)
                tile[kk * 264 + n8 + q] = f2b(ldin(src, srow * 256 + n8 + q, isf32));
        }
        __syncthreads();
        unsigned int packed[16];
        #pragma unroll
        for (int q = 0; q < 16; q++) {
            unsigned int lo = tile[(2 * q) * 264 + tid];
            unsigned int hi = tile[(2 * q + 1) * 264 + tid];
            packed[q] = lo | (hi << 16);
        }
        uint4* dst = (uint4*)(Wgt + (long)tid * 384 + k0);
        #pragma unroll
        for (int p = 0; p < 4; p++)
            dst[p] = make_uint4(packed[4*p], packed[4*p+1], packed[4*p+2], packed[4*p+3]);
    } else if (b < 204) {               // Xc f32 from X[...][2:4]
        float* Xc = (float*)(ws + WS_XC);
        #pragma unroll
        for (int p = 0; p < 4; p++) {
            int e = (b - 140) * 1024 + p * 256 + tid;
            int row = e >> 1, comp = e & 1;
            Xc[e] = ldin(X, row * 4 + 2 + comp, isf32);
        }
    } else if (b == 204) {              // consts + barrier reset
        float* bsocF = (float*)(ws + WS_BSOC);
        float* bgF   = (float*)(ws + WS_BG);
        float* WoutF = (float*)(ws + WS_WOUT);
        float* WembF = (float*)(ws + WS_WEMB);
        float* bembF = (float*)(ws + WS_BEMB);
        float* boutF = (float*)(ws + WS_BOUT);
        bsocF[tid] = ldin(bsoc, tid, isf32);
        bgF[tid]   = ldin(bih, tid, isf32) + ldin(bhh, tid, isf32);
        if (tid < 128) { WoutF[tid] = ldin(Wout, tid, isf32); WembF[tid] = ldin(Wemb, tid, isf32); }
        if (tid < 64)  bembF[tid] = ldin(bemb, tid, isf32);
        if (tid < 2)   boutF[tid] = ldin(bout, tid, isf32);
        if (tid == 0)  *(int*)(ws + WS_BAR) = 0;
    } else if (b < 221) {               // c0 -> c_ws f32
        float* c_ws = (float*)(ws + WS_CW);
        int base = (b - 205) * 4096 + tid * 16;
        #pragma unroll
        for (int p = 0; p < 16; p++) c_ws[base + p] = ldin(c0, base + p, isf32);
    } else if (b < 229) {               // h0 -> hbB + zb h-part (bf16)
        unsigned short* zb  = (unsigned short*)(ws + WS_ZB);
        unsigned short* hbB = (unsigned short*)(ws + WS_HBB);
        #pragma unroll
        for (int p = 0; p < 32; p++) {
            int e = (b - 221) * 8192 + p * 256 + tid;
            unsigned short v = f2b(ldin(h0, e, isf32));
            hbB[e] = v;
            zb[(e >> 6) * 384 + 320 + (e & 63)] = v;
        }
    } else {                            // zero d_out (dtype-sized)
        uint4 z = make_uint4(0u, 0u, 0u, 0u);
        uint4* p = (uint4*)out;
        int n16 = isf32 ? 16384 : 8192;
        for (int idx = (b - 229) * 256 + tid; idx < n16; idx += 2048) p[idx] = z;
    }
}

// ---------------- grid barrier (monotonic counter, device scope) ----------
__device__ __forceinline__ void gsync(int* bar, int target) {
    __threadfence();
    __syncthreads();
    if (threadIdx.x == 0) {
        __hip_atomic_fetch_add(bar, 1, __ATOMIC_ACQ_REL, __HIP_MEMORY_SCOPE_AGENT);
        while (__hip_atomic_load(bar, __ATOMIC_ACQUIRE, __HIP_MEMORY_SCOPE_AGENT) < target)
            __builtin_amdgcn_s_sleep(2);
    }
    __syncthreads();
    __threadfence();
}

// ---------------- persistent step kernel (grid 256) -----------------------
__global__ __launch_bounds__(256, 1) void k_step(char* __restrict__ ws,
                                                 const int* __restrict__ masks,
                                                 const void* __restrict__ Y,
                                                 const int* __restrict__ Tpred,
                                                 void* __restrict__ out) {
    float*          c_ws  = (float*)(ws + WS_CW);
    unsigned short* Wt    = (unsigned short*)(ws + WS_WT);
    unsigned short* Wgt   = (unsigned short*)(ws + WS_WGT);
    const float*    bsocF = (const float*)(ws + WS_BSOC);
    const float*    bgF   = (const float*)(ws + WS_BG);
    const float*    WoutF = (const float*)(ws + WS_WOUT);
    const float*    WembF = (const float*)(ws + WS_WEMB);
    const float*    bembF = (const float*)(ws + WS_BEMB);
    const float*    boutF = (const float*)(ws + WS_BOUT);
    int*            bar   = (int*)(ws + WS_BAR);
    const float*    Xc    = (const float*)(ws + WS_XC);
    unsigned short* zb    = (unsigned short*)(ws + WS_ZB);
    unsigned short* hbB   = (unsigned short*)(ws + WS_HBB);
    unsigned short* Hbuf  = (unsigned short*)(ws + WS_HBUF);
    float*          part  = (float*)(ws + WS_PART);

    int isf32 = *(const int*)(ws + WS_FLAG);
    int tp = get_tpred(Tpred); if (tp > 31) tp = 31;
    int bid = blockIdx.x, tid = threadIdx.x;
    int w = tid >> 6, lane = tid & 63;
    int nblk = (int)gridDim.x;
    int gen = 0;
    int mrow = lane & 15, q = lane >> 4;

    __shared__ __align__(16) char smem[46080];
    short* Asm = (short*)smem;                       // P2: [64][72]; P3: [32][72]
    short* Bsm = (short*)(smem + 9216);              // [256][72] / gLDS f32[32][256]

    for (int t = 0; t <= tp; t++) {
        // ============ P1: social pooling — one wave per agent =============
        {
            int i = bid * 4 + w;
            unsigned short* jlW   = (unsigned short*)smem + (w << 10);     // 2KB/wave
            int*            histW = (int*)(smem + 8192) + (w << 6);
            int*            stW   = (int*)(smem + 9216) + (w << 6);
            histW[lane] = 0;
            __syncthreads();
            float cix = Xc[(t * 1024 + i) * 2 + 0];
            float ciy = Xc[(t * 1024 + i) * 2 + 1];
            int mi = masks[t * 1024 + i];
            {   // r = relu(coords @ Wemb + bemb)
                float rv = fmaxf(WembF[lane] * cix + WembF[64 + lane] * ciy + bembF[lane], 0.f);
                zb[i * 384 + lane] = f2b(rv);
            }
            int cc[16];
            #pragma unroll
            for (int ch = 0; ch < 16; ch++) {
                int j = ch * 64 + lane;
                int c = -1;
                if (mi != 0 && j != i && masks[t * 1024 + j] != 0) {
                    float dx = Xc[(t * 1024 + j) * 2 + 0] - cix;
                    float dy = Xc[(t * 1024 + j) * 2 + 1] - ciy;
                    int g0 = (int)dx, g1 = (int)dy;      // trunc == jnp.trunc
                    if (g0 >= -3 && g0 <= 3 && g1 >= -3 && g1 <= 3)
                        c = (g0 + 3) * 7 + (g1 + 3);
                }
                cc[ch] = c;
                if (c >= 0) atomicAdd(&histW[c], 1);
            }
            __syncthreads();
            {   // exclusive scan of 64 bins (bins 49..63 zero)
                int x = histW[lane];
                int h0v = x;
                #pragma unroll
                for (int off = 1; off < 64; off <<= 1) {
                    int y = __shfl_up(x, off);
                    if (lane >= off) x += y;
                }
                stW[lane] = x - h0v;
            }
            __syncthreads();
            histW[lane] = stW[lane];                     // cur = starts
            __syncthreads();
            #pragma unroll
            for (int ch = 0; ch < 16; ch++) {
                int c = cc[ch];
                if (c >= 0) {
                    int pos = atomicAdd(&histW[c], 1);
                    jlW[pos] = (unsigned short)(ch * 64 + lane);
                }
            }
            __syncthreads();
            long hb = (long)i * 3136;
            for (int c = 0; c < 49; c++) {
                int k0 = stW[c], k1 = stW[c + 1];
                float acc = 0.f;
                int k = k0;
                for (; k + 16 <= k1; k += 16) {
                    int js[16];
                    #pragma unroll
                    for (int u = 0; u < 16; u++) js[u] = jlW[k + u];
                    float vs[16];
                    #pragma unroll
                    for (int u = 0; u < 16; u++) vs[u] = u2f(hbB[js[u] * 64 + lane]);
                    acc += (((vs[0]+vs[1])+(vs[2]+vs[3])) + ((vs[4]+vs[5])+(vs[6]+vs[7])))
                         + (((vs[8]+vs[9])+(vs[10]+vs[11])) + ((vs[12]+vs[13])+(vs[14]+vs[15])));
                }
                for (; k + 4 <= k1; k += 4) {
                    int j0 = jlW[k], j1 = jlW[k+1], j2 = jlW[k+2], j3 = jlW[k+3];
                    float v0 = u2f(hbB[j0 * 64 + lane]), v1 = u2f(hbB[j1 * 64 + lane]);
                    float v2 = u2f(hbB[j2 * 64 + lane]), v3 = u2f(hbB[j3 * 64 + lane]);
                    acc += (v0 + v1) + (v2 + v3);
                }
                for (; k < k1; k++) acc += u2f(hbB[jlW[k] * 64 + lane]);
                Hbuf[hb + c * 64 + lane] = f2b(acc);
            }
        }
        gsync(bar, ++gen * nblk);

        // ============ P2: part[s] = H-slice @ Wsoc (MFMA) =================
        if (bid < 128) {
            int s = bid & 7, rb = bid >> 3;
            int row0 = rb * 64;
            int m0 = (49 * s) >> 3, m1 = (49 * (s + 1)) >> 3;
            int wcol = w * 64;
            f32x4 acc[4][4];
            f32x4 zz = {0.f, 0.f, 0.f, 0.f};
            #pragma unroll
            for (int a = 0; a < 4; a++)
                #pragma unroll
                for (int b2 = 0; b2 < 4; b2++) acc[a][b2] = zz;
            for (int m = m0; m < m1; m++) {
                int wcell = ((m / 7) * 8 + (m % 7) + 9) * 64;
                __syncthreads();
                {
                    int row = tid >> 2;
                    #pragma unroll
                    for (int p = 0; p < 2; p++) {
                        int seg = (tid & 3) + (p << 2);
                        *(uint4*)&Asm[row * 72 + seg * 8] =
                            *(const uint4*)(Hbuf + (long)(row0 + row) * 3136 + m * 64 + seg * 8);
                    }
                    const unsigned short* src = Wt + (long)tid * 4096 + wcell;
                    #pragma unroll
                    for (int p = 0; p < 8; p++)
                        *(uint4*)&Bsm[tid * 72 + p * 8] = *(const uint4*)(src + p * 8);
                }
                __syncthreads();
                #pragma unroll
                for (int kc = 0; kc < 2; kc++) {
                    bf16x8 af[4];
                    #pragma unroll
                    for (int mt = 0; mt < 4; mt++)
                        af[mt] = *(bf16x8*)&Asm[(mt * 16 + mrow) * 72 + kc * 32 + q * 8];
                    #pragma unroll
                    for (int nt = 0; nt < 4; nt++) {
                        bf16x8 bv = *(bf16x8*)&Bsm[(wcol + nt * 16 + mrow) * 72 + kc * 32 + q * 8];
                        #pragma unroll
                        for (int mt = 0; mt < 4; mt++)
                            acc[mt][nt] = __builtin_amdgcn_mfma_f32_16x16x32_bf16(af[mt], bv, acc[mt][nt], 0, 0, 0);
                    }
                }
            }
            float* ps = part + (long)s * 262144;
            #pragma unroll
            for (int mt = 0; mt < 4; mt++)
                #pragma unroll
                for (int nt = 0; nt < 4; nt++)
                    #pragma unroll
                    for (int r = 0; r < 4; r++)
                        ps[(row0 + mt * 16 + q * 4 + r) * 256 + (wcol + nt * 16 + mrow)] = acc[mt][nt][r];
        }
        gsync(bar, ++gen * nblk);

        // ============ P3: e-reduce + gates MFMA + LSTM cell + out =========
        if (bid < 32) {
            int row0 = bid * 32;
            int wcol = w * 64;
            f32x4 acc[2][4];
            f32x4 zz = {0.f, 0.f, 0.f, 0.f};
            #pragma unroll
            for (int a = 0; a < 2; a++)
                #pragma unroll
                for (int b2 = 0; b2 < 4; b2++) acc[a][b2] = zz;
            for (int kc = 0; kc < 6; kc++) {
                __syncthreads();
                if (kc == 0 || kc == 5) {
                    int zofs = (kc == 0) ? 0 : 320;
                    int r = tid >> 3, seg = tid & 7;
                    *(uint4*)&Asm[r * 72 + seg * 8] =
                        *(const uint4*)(zb + (long)(row0 + r) * 384 + zofs + seg * 8);
                } else {
                    int r = tid >> 3, q8 = tid & 7;
                    int ecol = (kc - 1) * 64 + q8 * 8;
                    float4 a0 = *(const float4*)(bsocF + ecol);
                    float4 a1 = *(const float4*)(bsocF + ecol + 4);
                    #pragma unroll
                    for (int ss = 0; ss < 8; ss++) {
                        const float* pb = part + (long)ss * 262144 + (row0 + r) * 256 + ecol;
                        float4 u0 = *(const float4*)pb;
                        float4 u1 = *(const float4*)(pb + 4);
                        a0.x += u0.x; a0.y += u0.y; a0.z += u0.z; a0.w += u0.w;
                        a1.x += u1.x; a1.y += u1.y; a1.z += u1.z; a1.w += u1.w;
                    }
                    unsigned int p0 = f2b(fmaxf(a0.x, 0.f)) | ((unsigned int)f2b(fmaxf(a0.y, 0.f)) << 16);
                    unsigned int p1 = f2b(fmaxf(a0.z, 0.f)) | ((unsigned int)f2b(fmaxf(a0.w, 0.f)) << 16);
                    unsigned int p2 = f2b(fmaxf(a1.x, 0.f)) | ((unsigned int)f2b(fmaxf(a1.y, 0.f)) << 16);
                    unsigned int p3 = f2b(fmaxf(a1.z, 0.f)) | ((unsigned int)f2b(fmaxf(a1.w, 0.f)) << 16);
                    *(uint4*)&Asm[r * 72 + q8 * 8] = make_uint4(p0, p1, p2, p3);
                }
                {
                    const unsigned short* src = Wgt + (long)tid * 384 + kc * 64;
                    #pragma unroll
                    for (int p = 0; p < 8; p++)
                        *(uint4*)&Bsm[tid * 72 + p * 8] = *(const uint4*)(src + p * 8);
                }
                __syncthreads();
                #pragma unroll
                for (int kc2 = 0; kc2 < 2; kc2++) {
                    bf16x8 af[2];
                    af[0] = *(bf16x8*)&Asm[(mrow) * 72 + kc2 * 32 + q * 8];
                    af[1] = *(bf16x8*)&Asm[(16 + mrow) * 72 + kc2 * 32 + q * 8];
                    #pragma unroll
                    for (int nt = 0; nt < 4; nt++) {
                        bf16x8 bv = *(bf16x8*)&Bsm[(wcol + nt * 16 + mrow) * 72 + kc2 * 32 + q * 8];
                        acc[0][nt] = __builtin_amdgcn_mfma_f32_16x16x32_bf16(af[0], bv, acc[0][nt], 0, 0, 0);
                        acc[1][nt] = __builtin_amdgcn_mfma_f32_16x16x32_bf16(af[1], bv, acc[1][nt], 0, 0, 0);
                    }
                }
            }
            __syncthreads();
            float* gL = (float*)(smem + 9216);           // [32][256] f32
            #pragma unroll
            for (int mt = 0; mt < 2; mt++)
                #pragma unroll
                for (int nt = 0; nt < 4; nt++)
                    #pragma unroll
                    for (int r = 0; r < 4; r++)
                        gL[(mt * 16 + q * 4 + r) * 256 + (wcol + nt * 16 + mrow)] = acc[mt][nt][r];
            __syncthreads();
            for (int rr = 0; rr < 8; rr++) {
                int lr = w * 8 + rr;
                int row = row0 + lr;
                float gi = gL[lr * 256 + lane]       + bgF[lane];
                float gf = gL[lr * 256 + 64 + lane]  + bgF[64 + lane];
                float gg = gL[lr * 256 + 128 + lane] + bgF[128 + lane];
                float go = gL[lr * 256 + 192 + lane] + bgF[192 + lane];
                float c  = c_ws[row * 64 + lane];
                float si = 1.f / (1.f + __expf(-gi));
                float sf = 1.f / (1.f + __expf(-gf));
                float so = 1.f / (1.f + __expf(-go));
                float cn = sf * c + si * tanhf(gg);
                float hn = so * tanhf(cn);
                c_ws[row * 64 + lane] = cn;
                unsigned short hB = f2b(hn);
                hbB[row * 64 + lane] = hB;
                zb[row * 384 + 320 + lane] = hB;
                float p0 = hn * WoutF[lane * 2 + 0];
                float p1 = hn * WoutF[lane * 2 + 1];
                #pragma unroll
                for (int o = 32; o >= 1; o >>= 1) {
                    p0 += __shfl_xor(p0, o);
                    p1 += __shfl_xor(p1, o);
                }
                if (lane == 0) {
                    int m = masks[t * 1024 + row];
                    float o0 = 0.f, o1 = 0.f;
                    if (m != 0) {
                        bool appear = (t > 3) && (masks[(t - 3) * 1024 + row] == 0);
                        if (appear) {
                            o0 = ldin(Y, (t * 1024 + row) * 2 + 0, isf32);
                            o1 = ldin(Y, (t * 1024 + row) * 2 + 1, isf32);
                        } else {
                            o0 = p0 + boutF[0];
                            o1 = p1 + boutF[1];
                        }
                    }
                    if (!(o0 == o0)) o0 = 0.f;
                    if (!(o1 == o1)) o1 = 0.f;
                    int ofs = (t * 1024 + row) * 2;
                    if (isf32) {
                        ((float*)out)[ofs + 0] = o0;
                        ((float*)out)[ofs + 1] = o1;
                    } else {
                        ((unsigned short*)out)[ofs + 0] = f2b(o0);
                        ((unsigned short*)out)[ofs + 1] = f2b(o1);
                    }
                }
            }
        }
        gsync(bar, ++gen * nblk);
    }
}

extern "C" void kernel_launch(void* const* d_in, const int* in_sizes, int n_in,
                              void* d_out, int out_size, void* d_ws, size_t ws_size,
                              hipStream_t stream) {
    (void)in_sizes; (void)n_in; (void)out_size; (void)ws_size;
    const void* X     = d_in[0];
    const int*  masks = (const int*)d_in[1];
    const void* h0    = d_in[2];
    const void* c0    = d_in[3];
    const void* Y     = d_in[4];
    const int*  Tpred = (const int*)d_in[6];
    const void* Wemb  = d_in[7];
    const void* bemb  = d_in[8];
    const void* Wsoc  = d_in[9];
    const void* bsoc  = d_in[10];
    const void* Wih   = d_in[11];
    const void* bih   = d_in[12];
    const void* Whh   = d_in[13];
    const void* bhh   = d_in[14];
    const void* Wout  = d_in[15];
    const void* bout  = d_in[16];

    char* ws = (char*)d_ws;
    int* flag = (int*)(ws + WS_FLAG);

    k_detect<<<1, 256, 0, stream>>>(Wsoc, flag);
    k_prep<<<237, 256, 0, stream>>>(ws, X, h0, c0, Wsoc, Wih, Whh, bih, bhh,
                                    bsoc, Wemb, bemb, Wout, bout, d_out);
    k_step<<<256, 256, 0, stream>>>(ws, masks, Y, Tpred, d_out);
}

// Round 7
// 1795.558 us; speedup vs baseline: 6.0999x; 6.0999x over previous
//
#include <hip/hip_runtime.h>
#include <hip/hip_bf16.h>

// SocialLSTM forward, MI355X gfx950 — multi-kernel (3/step), r6-verified phases.
// Dual-dtype float inputs (bf16 or f32) detected at runtime from W_soc.
// ws layout (bytes):
//   c_ws  f32[1024*64]      @ 0
//   Wt    bf16[256][4096]   @ 262144   (W_soc^T, [n][k])
//   Wgt   bf16[256][384]    @ 2359296  ([Wih;Whh]^T, [n][k])
//   bsocF f32[256]          @ 2555904
//   bgF   f32[256]          @ 2556928  (bih+bhh)
//   WoutF f32[128]          @ 2557952
//   WembF f32[128]          @ 2558464
//   bembF f32[64]           @ 2558976
//   boutF f32[2]            @ 2559232
//   flag  int               @ 2559244
//   Xc    f32[32][1024][2]  @ 2560000
//   zb    bf16[1024][384]   @ 2822144  (r cols 0-63, h cols 320-383)
//   hbB   bf16[1024][64]    @ 3608576  (compact h for pooling gathers)
//   Hbuf  bf16[1024][3136]  @ 3739648  (49 cells * 64 hid per row)
//   part  f32[8][1024*256]  @ 10162176 (K-split GEMM partials)

typedef short bf16x8 __attribute__((ext_vector_type(8)));
typedef float f32x4 __attribute__((ext_vector_type(4)));

#define WS_CW    0
#define WS_WT    262144
#define WS_WGT   2359296
#define WS_BSOC  2555904
#define WS_BG    2556928
#define WS_WOUT  2557952
#define WS_WEMB  2558464
#define WS_BEMB  2558976
#define WS_BOUT  2559232
#define WS_BAR   2559240
#define WS_FLAG  2559244
#define WS_XC    2560000
#define WS_ZB    2822144
#define WS_HBB   3608576
#define WS_HBUF  3739648
#define WS_PART  10162176

__device__ __forceinline__ float u2f(unsigned short u) {
    union { unsigned int i; float f; } v; v.i = ((unsigned int)u) << 16; return v.f;
}
__device__ __forceinline__ unsigned short f2b(float f) {
    __hip_bfloat16 hb = __float2bfloat16(f);
    return *(unsigned short*)&hb;
}
__device__ __forceinline__ float ldin(const void* p, int idx, int isf32) {
    return isf32 ? ((const float*)p)[idx] : u2f(((const unsigned short*)p)[idx]);
}
__device__ __forceinline__ int get_tpred(const int* p) {
    int v = p[0];
    if (v >= 0 && v <= 64) return v;
    float f = ((const float*)p)[0];
    if (f >= 0.f && f <= 64.f) return (int)f;
    float g = u2f(((const unsigned short*)p)[0]);
    if (g >= 0.f && g <= 64.f) return (int)g;
    return 31;
}

// ---------------- dtype detector ------------------------------------------
__global__ __launch_bounds__(256) void k_detect(const void* __restrict__ Wsoc,
                                                int* __restrict__ flag) {
    __shared__ int f;
    int tid = threadIdx.x;
    if (tid == 0) f = 0;
    __syncthreads();
    const unsigned short* p = (const unsigned short*)Wsoc;
    #pragma unroll
    for (int k = 0; k < 4; k++) {
        float v = u2f(p[tid * 4 + k]);
        if (!(v == v) || fabsf(v) > 1e20f) f = 1;
    }
    __syncthreads();
    if (tid == 0) flag[0] = f;
}

// ---------------- one-time prep (block-ranged, 237 blocks) ----------------
__global__ __launch_bounds__(256) void k_prep(char* __restrict__ ws,
                                              const void* __restrict__ X,
                                              const void* __restrict__ h0,
                                              const void* __restrict__ c0,
                                              const void* __restrict__ Wsoc,
                                              const void* __restrict__ Wih,
                                              const void* __restrict__ Whh,
                                              const void* __restrict__ bih,
                                              const void* __restrict__ bhh,
                                              const void* __restrict__ bsoc,
                                              const void* __restrict__ Wemb,
                                              const void* __restrict__ bemb,
                                              const void* __restrict__ Wout,
                                              const void* __restrict__ bout,
                                              void* __restrict__ out) {
    __shared__ __align__(16) unsigned short tile[32 * 264];
    int b = blockIdx.x, tid = threadIdx.x;
    int isf32 = *(const int*)(ws + WS_FLAG);
    if (b < 128) {                      // Wt = Wsoc^T
        unsigned short* Wt = (unsigned short*)(ws + WS_WT);
        int k0 = b * 32;
        if (isf32) {
            const float* W = (const float*)Wsoc;
            #pragma unroll
            for (int p = 0; p < 4; p++) {
                int kk = (tid >> 5) + p * 8, n8 = (tid & 31) * 8;
                #pragma unroll
                for (int q = 0; q < 8; q++)
                    tile[kk * 264 + n8 + q] = f2b(W[(k0 + kk) * 256 + n8 + q]);
            }
        } else {
            const unsigned short* W = (const unsigned short*)Wsoc;
            #pragma unroll
            for (int p = 0; p < 4; p++) {
                int kk = (tid >> 5) + p * 8, n8 = (tid & 31) * 8;
                *(uint4*)&tile[kk * 264 + n8] = *(const uint4*)(W + (k0 + kk) * 256 + n8);
            }
        }
        __syncthreads();
        unsigned int packed[16];
        #pragma unroll
        for (int q = 0; q < 16; q++) {
            unsigned int lo = tile[(2 * q) * 264 + tid];
            unsigned int hi = tile[(2 * q + 1) * 264 + tid];
            packed[q] = lo | (hi << 16);
        }
        uint4* dst = (uint4*)(Wt + (long)tid * 4096 + k0);
        #pragma unroll
        for (int p = 0; p < 4; p++)
            dst[p] = make_uint4(packed[4*p], packed[4*p+1], packed[4*p+2], packed[4*p+3]);
    } else if (b < 140) {               // Wgt = [Wih;Whh]^T
        unsigned short* Wgt = (unsigned short*)(ws + WS_WGT);
        int k0 = (b - 128) * 32;
        #pragma unroll
        for (int p = 0; p < 4; p++) {
            int kk = (tid >> 5) + p * 8, n8 = (tid & 31) * 8;
            int krow = k0 + kk;
            const void* src = (krow < 320) ? Wih : Whh;
            int srow = (krow < 320) ? krow : (krow - 320);
            #pragma unroll
            for (int q = 0; q < 8; q++)
                tile[kk * 264 + n8 + q] = f2b(ldin(src, srow * 256 + n8 + q, isf32));
        }
        __syncthreads();
        unsigned int packed[16];
        #pragma unroll
        for (int q = 0; q < 16; q++) {
            unsigned int lo = tile[(2 * q) * 264 + tid];
            unsigned int hi = tile[(2 * q + 1) * 264 + tid];
            packed[q] = lo | (hi << 16);
        }
        uint4* dst = (uint4*)(Wgt + (long)tid * 384 + k0);
        #pragma unroll
        for (int p = 0; p < 4; p++)
            dst[p] = make_uint4(packed[4*p], packed[4*p+1], packed[4*p+2], packed[4*p+3]);
    } else if (b < 204) {               // Xc f32 from X[...][2:4]
        float* Xc = (float*)(ws + WS_XC);
        #pragma unroll
        for (int p = 0; p < 4; p++) {
            int e = (b - 140) * 1024 + p * 256 + tid;
            int row = e >> 1, comp = e & 1;
            Xc[e] = ldin(X, row * 4 + 2 + comp, isf32);
        }
    } else if (b == 204) {              // consts
        float* bsocF = (float*)(ws + WS_BSOC);
        float* bgF   = (float*)(ws + WS_BG);
        float* WoutF = (float*)(ws + WS_WOUT);
        float* WembF = (float*)(ws + WS_WEMB);
        float* bembF = (float*)(ws + WS_BEMB);
        float* boutF = (float*)(ws + WS_BOUT);
        bsocF[tid] = ldin(bsoc, tid, isf32);
        bgF[tid]   = ldin(bih, tid, isf32) + ldin(bhh, tid, isf32);
        if (tid < 128) { WoutF[tid] = ldin(Wout, tid, isf32); WembF[tid] = ldin(Wemb, tid, isf32); }
        if (tid < 64)  bembF[tid] = ldin(bemb, tid, isf32);
        if (tid < 2)   boutF[tid] = ldin(bout, tid, isf32);
        if (tid == 0)  *(int*)(ws + WS_BAR) = 0;
    } else if (b < 221) {               // c0 -> c_ws f32
        float* c_ws = (float*)(ws + WS_CW);
        int base = (b - 205) * 4096 + tid * 16;
        #pragma unroll
        for (int p = 0; p < 16; p++) c_ws[base + p] = ldin(c0, base + p, isf32);
    } else if (b < 229) {               // h0 -> hbB + zb h-part (bf16)
        unsigned short* zb  = (unsigned short*)(ws + WS_ZB);
        unsigned short* hbB = (unsigned short*)(ws + WS_HBB);
        #pragma unroll
        for (int p = 0; p < 32; p++) {
            int e = (b - 221) * 8192 + p * 256 + tid;
            unsigned short v = f2b(ldin(h0, e, isf32));
            hbB[e] = v;
            zb[(e >> 6) * 384 + 320 + (e & 63)] = v;
        }
    } else {                            // zero d_out (dtype-sized)
        uint4 z = make_uint4(0u, 0u, 0u, 0u);
        uint4* p = (uint4*)out;
        int n16 = isf32 ? 16384 : 8192;
        for (int idx = (b - 229) * 256 + tid; idx < n16; idx += 2048) p[idx] = z;
    }
}

// ---------------- per step: social pooling (grid 1024) --------------------
// r4-proven ballot compaction; bf16 gathers from hbB; writes zb r-part.
__global__ __launch_bounds__(256) void k_pool(const float* __restrict__ Xc,
                                              const int* __restrict__ masks,
                                              const float* __restrict__ WembF,
                                              const float* __restrict__ bembF,
                                              const int* __restrict__ Tpred,
                                              const unsigned short* __restrict__ hbB,
                                              unsigned short* __restrict__ zb,
                                              unsigned short* __restrict__ Hbuf,
                                              int t) {
    if (t > get_tpred(Tpred)) return;
    int i = blockIdx.x, tid = threadIdx.x;
    __shared__ unsigned char code[1024];
    __shared__ unsigned short jl[4][1024];
    int mi = masks[t * 1024 + i];
    float cix = Xc[(t * 1024 + i) * 2 + 0];
    float ciy = Xc[(t * 1024 + i) * 2 + 1];
    if (tid < 64) {
        float rv = fmaxf(WembF[tid] * cix + WembF[64 + tid] * ciy + bembF[tid], 0.f);
        zb[i * 384 + tid] = f2b(rv);
    }
    if (mi != 0) {
        #pragma unroll
        for (int p = 0; p < 4; p++) {
            int j = tid + p * 256;
            unsigned char cc = 0xFF;
            if (j != i && masks[t * 1024 + j] != 0) {
                float dx = Xc[(t * 1024 + j) * 2 + 0] - cix;
                float dy = Xc[(t * 1024 + j) * 2 + 1] - ciy;
                int g0 = (int)dx, g1 = (int)dy;   // trunc toward zero == jnp.trunc
                if (g0 >= -3 && g0 <= 3 && g1 >= -3 && g1 <= 3)
                    cc = (unsigned char)((g0 + 3) * 7 + (g1 + 3));   // dense 0..48
            }
            code[j] = cc;
        }
    }
    __syncthreads();
    int w = tid >> 6, lane = tid & 63;
    long hb_base = (long)i * 3136;
    if (mi == 0) {   // block-uniform: H row all zeros
        unsigned int* hp = (unsigned int*)(Hbuf + hb_base);
        for (int idx = tid; idx < 1568; idx += 256) hp[idx] = 0u;
        return;
    }
    unsigned int creg[16];
    #pragma unroll
    for (int ch = 0; ch < 16; ch++) creg[ch] = code[ch * 64 + lane];
    unsigned short* wl = jl[w];
    for (int c = w; c < 49; c += 4) {       // round-robin cells over 4 waves
        int n = 0;
        #pragma unroll
        for (int ch = 0; ch < 16; ch++) {
            bool p = (creg[ch] == (unsigned int)c);
            unsigned long long m = __ballot(p);
            if (p) {
                int rank = __popcll(m & ((1ull << lane) - 1ull));
                wl[n + rank] = (unsigned short)(ch * 64 + lane);
            }
            n += (int)__popcll(m);
        }
        float acc = 0.f;
        int k = 0;
        for (; k + 8 <= n; k += 8) {        // 8 loads in flight
            int j0 = wl[k], j1 = wl[k + 1], j2 = wl[k + 2], j3 = wl[k + 3];
            int j4 = wl[k + 4], j5 = wl[k + 5], j6 = wl[k + 6], j7 = wl[k + 7];
            float v0 = u2f(hbB[j0 * 64 + lane]), v1 = u2f(hbB[j1 * 64 + lane]);
            float v2 = u2f(hbB[j2 * 64 + lane]), v3 = u2f(hbB[j3 * 64 + lane]);
            float v4 = u2f(hbB[j4 * 64 + lane]), v5 = u2f(hbB[j5 * 64 + lane]);
            float v6 = u2f(hbB[j6 * 64 + lane]), v7 = u2f(hbB[j7 * 64 + lane]);
            acc += ((v0 + v1) + (v2 + v3)) + ((v4 + v5) + (v6 + v7));
        }
        for (; k < n; k++) acc += u2f(hbB[wl[k] * 64 + lane]);
        Hbuf[hb_base + c * 64 + lane] = f2b(acc);
    }
}

// ---------------- per step: part[s] = H-slice @ Wsoc (grid 128, MFMA) -----
__global__ __launch_bounds__(256) void k_gemm(const unsigned short* __restrict__ Hbuf,
                                              const unsigned short* __restrict__ Wt,
                                              const int* __restrict__ Tpred,
                                              float* __restrict__ part,
                                              int t) {
    if (t > get_tpred(Tpred)) return;
    int bid = blockIdx.x, tid = threadIdx.x;
    int w = tid >> 6, lane = tid & 63;
    int mrow = lane & 15, q = lane >> 4;
    __shared__ __align__(16) char smem[46080];
    short* Asm = (short*)smem;                       // [64][72]
    short* Bsm = (short*)(smem + 9216);              // [256][72]
    int s = bid & 7, rb = bid >> 3;
    int row0 = rb * 64;
    int m0 = (49 * s) >> 3, m1 = (49 * (s + 1)) >> 3;
    int wcol = w * 64;
    f32x4 acc[4][4];
    f32x4 zz = {0.f, 0.f, 0.f, 0.f};
    #pragma unroll
    for (int a = 0; a < 4; a++)
        #pragma unroll
        for (int b2 = 0; b2 < 4; b2++) acc[a][b2] = zz;
    for (int m = m0; m < m1; m++) {
        int wcell = ((m / 7) * 8 + (m % 7) + 9) * 64;
        __syncthreads();
        {
            int row = tid >> 2;
            #pragma unroll
            for (int p = 0; p < 2; p++) {
                int seg = (tid & 3) + (p << 2);
                *(uint4*)&Asm[row * 72 + seg * 8] =
                    *(const uint4*)(Hbuf + (long)(row0 + row) * 3136 + m * 64 + seg * 8);
            }
            const unsigned short* src = Wt + (long)tid * 4096 + wcell;
            #pragma unroll
            for (int p = 0; p < 8; p++)
                *(uint4*)&Bsm[tid * 72 + p * 8] = *(const uint4*)(src + p * 8);
        }
        __syncthreads();
        #pragma unroll
        for (int kc = 0; kc < 2; kc++) {
            bf16x8 af[4];
            #pragma unroll
            for (int mt = 0; mt < 4; mt++)
                af[mt] = *(bf16x8*)&Asm[(mt * 16 + mrow) * 72 + kc * 32 + q * 8];
            #pragma unroll
            for (int nt = 0; nt < 4; nt++) {
                bf16x8 bv = *(bf16x8*)&Bsm[(wcol + nt * 16 + mrow) * 72 + kc * 32 + q * 8];
                #pragma unroll
                for (int mt = 0; mt < 4; mt++)
                    acc[mt][nt] = __builtin_amdgcn_mfma_f32_16x16x32_bf16(af[mt], bv, acc[mt][nt], 0, 0, 0);
            }
        }
    }
    float* ps = part + (long)s * 262144;
    #pragma unroll
    for (int mt = 0; mt < 4; mt++)
        #pragma unroll
        for (int nt = 0; nt < 4; nt++)
            #pragma unroll
            for (int r = 0; r < 4; r++)
                ps[(row0 + mt * 16 + q * 4 + r) * 256 + (wcol + nt * 16 + mrow)] = acc[mt][nt][r];
}

// ---------------- per step: e-reduce + gates MFMA + cell + out (grid 32) --
__global__ __launch_bounds__(256) void k_gc(const int* __restrict__ masks,
                                            const void* __restrict__ Y,
                                            const float* __restrict__ part,
                                            const unsigned short* __restrict__ Wgt,
                                            const float* __restrict__ bsocF,
                                            const float* __restrict__ bgF,
                                            const float* __restrict__ WoutF,
                                            const float* __restrict__ boutF,
                                            float* __restrict__ c_ws,
                                            unsigned short* __restrict__ zb,
                                            unsigned short* __restrict__ hbB,
                                            const int* __restrict__ Tpred,
                                            const int* __restrict__ flag,
                                            void* __restrict__ out,
                                            int t) {
    if (t > get_tpred(Tpred)) return;
    int isf32 = flag[0];
    int bid = blockIdx.x, tid = threadIdx.x;
    int w = tid >> 6, lane = tid & 63;
    int mrow = lane & 15, q = lane >> 4;
    __shared__ __align__(16) char smem[46080];
    short* Asm = (short*)smem;                       // [32][72]
    short* Bsm = (short*)(smem + 9216);              // [256][72]
    int row0 = bid * 32;
    int wcol = w * 64;
    f32x4 acc[2][4];
    f32x4 zz = {0.f, 0.f, 0.f, 0.f};
    #pragma unroll
    for (int a = 0; a < 2; a++)
        #pragma unroll
        for (int b2 = 0; b2 < 4; b2++) acc[a][b2] = zz;
    for (int kc = 0; kc < 6; kc++) {
        __syncthreads();
        if (kc == 0 || kc == 5) {
            int zofs = (kc == 0) ? 0 : 320;
            int r = tid >> 3, seg = tid & 7;
            *(uint4*)&Asm[r * 72 + seg * 8] =
                *(const uint4*)(zb + (long)(row0 + r) * 384 + zofs + seg * 8);
        } else {
            int r = tid >> 3, q8 = tid & 7;
            int ecol = (kc - 1) * 64 + q8 * 8;
            float4 a0 = *(const float4*)(bsocF + ecol);
            float4 a1 = *(const float4*)(bsocF + ecol + 4);
            #pragma unroll
            for (int ss = 0; ss < 8; ss++) {
                const float* pb = part + (long)ss * 262144 + (row0 + r) * 256 + ecol;
                float4 u0 = *(const float4*)pb;
                float4 u1 = *(const float4*)(pb + 4);
                a0.x += u0.x; a0.y += u0.y; a0.z += u0.z; a0.w += u0.w;
                a1.x += u1.x; a1.y += u1.y; a1.z += u1.z; a1.w += u1.w;
            }
            unsigned int p0 = f2b(fmaxf(a0.x, 0.f)) | ((unsigned int)f2b(fmaxf(a0.y, 0.f)) << 16);
            unsigned int p1 = f2b(fmaxf(a0.z, 0.f)) | ((unsigned int)f2b(fmaxf(a0.w, 0.f)) << 16);
            unsigned int p2 = f2b(fmaxf(a1.x, 0.f)) | ((unsigned int)f2b(fmaxf(a1.y, 0.f)) << 16);
            unsigned int p3 = f2b(fmaxf(a1.z, 0.f)) | ((unsigned int)f2b(fmaxf(a1.w, 0.f)) << 16);
            *(uint4*)&Asm[r * 72 + q8 * 8] = make_uint4(p0, p1, p2, p3);
        }
        {
            const unsigned short* src = Wgt + (long)tid * 384 + kc * 64;
            #pragma unroll
            for (int p = 0; p < 8; p++)
                *(uint4*)&Bsm[tid * 72 + p * 8] = *(const uint4*)(src + p * 8);
        }
        __syncthreads();
        #pragma unroll
        for (int kc2 = 0; kc2 < 2; kc2++) {
            bf16x8 af[2];
            af[0] = *(bf16x8*)&Asm[(mrow) * 72 + kc2 * 32 + q * 8];
            af[1] = *(bf16x8*)&Asm[(16 + mrow) * 72 + kc2 * 32 + q * 8];
            #pragma unroll
            for (int nt = 0; nt < 4; nt++) {
                bf16x8 bv = *(bf16x8*)&Bsm[(wcol + nt * 16 + mrow) * 72 + kc2 * 32 + q * 8];
                acc[0][nt] = __builtin_amdgcn_mfma_f32_16x16x32_bf16(af[0], bv, acc[0][nt], 0, 0, 0);
                acc[1][nt] = __builtin_amdgcn_mfma_f32_16x16x32_bf16(af[1], bv, acc[1][nt], 0, 0, 0);
            }
        }
    }
    __syncthreads();
    float* gL = (float*)(smem + 9216);               // [32][256] f32 (over Bsm)
    #pragma unroll
    for (int mt = 0; mt < 2; mt++)
        #pragma unroll
        for (int nt = 0; nt < 4; nt++)
            #pragma unroll
            for (int r = 0; r < 4; r++)
                gL[(mt * 16 + q * 4 + r) * 256 + (wcol + nt * 16 + mrow)] = acc[mt][nt][r];
    __syncthreads();
    for (int rr = 0; rr < 8; rr++) {
        int lr = w * 8 + rr;
        int row = row0 + lr;
        float gi = gL[lr * 256 + lane]       + bgF[lane];
        float gf = gL[lr * 256 + 64 + lane]  + bgF[64 + lane];
        float gg = gL[lr * 256 + 128 + lane] + bgF[128 + lane];
        float go = gL[lr * 256 + 192 + lane] + bgF[192 + lane];
        float c  = c_ws[row * 64 + lane];
        float si = 1.f / (1.f + __expf(-gi));
        float sf = 1.f / (1.f + __expf(-gf));
        float so = 1.f / (1.f + __expf(-go));
        float cn = sf * c + si * tanhf(gg);
        float hn = so * tanhf(cn);
        c_ws[row * 64 + lane] = cn;
        unsigned short hB = f2b(hn);
        hbB[row * 64 + lane] = hB;
        zb[row * 384 + 320 + lane] = hB;
        float p0 = hn * WoutF[lane * 2 + 0];
        float p1 = hn * WoutF[lane * 2 + 1];
        #pragma unroll
        for (int o = 32; o >= 1; o >>= 1) {
            p0 += __shfl_xor(p0, o);
            p1 += __shfl_xor(p1, o);
        }
        if (lane == 0) {
            int m = masks[t * 1024 + row];
            float o0 = 0.f, o1 = 0.f;
            if (m != 0) {
                bool appear = (t > 3) && (masks[(t - 3) * 1024 + row] == 0);
                if (appear) {
                    o0 = ldin(Y, (t * 1024 + row) * 2 + 0, isf32);
                    o1 = ldin(Y, (t * 1024 + row) * 2 + 1, isf32);
                } else {
                    o0 = p0 + boutF[0];
                    o1 = p1 + boutF[1];
                }
            }
            if (!(o0 == o0)) o0 = 0.f;
            if (!(o1 == o1)) o1 = 0.f;
            int ofs = (t * 1024 + row) * 2;
            if (isf32) {
                ((float*)out)[ofs + 0] = o0;
                ((float*)out)[ofs + 1] = o1;
            } else {
                ((unsigned short*)out)[ofs + 0] = f2b(o0);
                ((unsigned short*)out)[ofs + 1] = f2b(o1);
            }
        }
    }
}

extern "C" void kernel_launch(void* const* d_in, const int* in_sizes, int n_in,
                              void* d_out, int out_size, void* d_ws, size_t ws_size,
                              hipStream_t stream) {
    (void)in_sizes; (void)n_in; (void)out_size; (void)ws_size;
    const void* X     = d_in[0];
    const int*  masks = (const int*)d_in[1];
    const void* h0    = d_in[2];
    const void* c0    = d_in[3];
    const void* Y     = d_in[4];
    const int*  Tpred = (const int*)d_in[6];
    const void* Wemb  = d_in[7];
    const void* bemb  = d_in[8];
    const void* Wsoc  = d_in[9];
    const void* bsoc  = d_in[10];
    const void* Wih   = d_in[11];
    const void* bih   = d_in[12];
    const void* Whh   = d_in[13];
    const void* bhh   = d_in[14];
    const void* Wout  = d_in[15];
    const void* bout  = d_in[16];

    char* ws = (char*)d_ws;
    int*            flag  = (int*)(ws + WS_FLAG);
    float*          c_ws  = (float*)(ws + WS_CW);
    unsigned short* Wt    = (unsigned short*)(ws + WS_WT);
    unsigned short* Wgt   = (unsigned short*)(ws + WS_WGT);
    const float*    bsocF = (const float*)(ws + WS_BSOC);
    const float*    bgF   = (const float*)(ws + WS_BG);
    const float*    WoutF = (const float*)(ws + WS_WOUT);
    const float*    WembF = (const float*)(ws + WS_WEMB);
    const float*    bembF = (const float*)(ws + WS_BEMB);
    const float*    boutF = (const float*)(ws + WS_BOUT);
    const float*    Xc    = (const float*)(ws + WS_XC);
    unsigned short* zb    = (unsigned short*)(ws + WS_ZB);
    unsigned short* hbB   = (unsigned short*)(ws + WS_HBB);
    unsigned short* Hbuf  = (unsigned short*)(ws + WS_HBUF);
    float*          part  = (float*)(ws + WS_PART);

    k_detect<<<1, 256, 0, stream>>>(Wsoc, flag);
    k_prep<<<237, 256, 0, stream>>>(ws, X, h0, c0, Wsoc, Wih, Whh, bih, bhh,
                                    bsoc, Wemb, bemb, Wout, bout, d_out);
    for (int t = 0; t < 32; t++) {
        k_pool<<<1024, 256, 0, stream>>>(Xc, masks, WembF, bembF, Tpred,
                                         hbB, zb, Hbuf, t);
        k_gemm<<<128, 256, 0, stream>>>(Hbuf, Wt, Tpred, part, t);
        k_gc<<<32, 256, 0, stream>>>(masks, Y, part, Wgt, bsocF, bgF, WoutF, boutF,
                                     c_ws, zb, hbB, Tpred, flag, d_out, t);
    }
}